// Round 1
// baseline (434.840 us; speedup 1.0000x reference)
//
#include <hip/hip_runtime.h>

// Problem constants (fixed by the reference)
#define H_DIM   1024
#define G_DIM   128
#define N_DIM   384          // 3*G
#define M_TOTAL 65536        // 32*2048 rows
#define BM      64           // rows per block
#define LDA     72           // LDS A row stride in halfs (64 + 8 pad)

typedef _Float16 half8  __attribute__((ext_vector_type(8)));
typedef float    f32x4  __attribute__((ext_vector_type(4)));

__device__ __forceinline__ float sigmoidf_(float v) {
    return 1.0f / (1.0f + __expf(-v));
}

// Convert weight_ih (384x1024 fp32, row-major, i.e. B^T with K contiguous)
// into f16 fragments, fragment-linear: frag index (ct*32 + ktg), 64 lanes x 8 halfs.
// Lane holds B^T[col = ct*16 + (lane&15)][k = ktg*32 + (lane>>4)*8 ... +8].
__global__ __launch_bounds__(256) void prep_w_kernel(const float* __restrict__ w,
                                                     _Float16* __restrict__ wf) {
    int gid  = blockIdx.x * 256 + threadIdx.x;   // 0 .. 49151
    int lane = gid & 63;
    int fid  = gid >> 6;
    int ktg  = fid & 31;
    int ct   = fid >> 5;
    int col  = ct * 16 + (lane & 15);
    int kb   = ktg * 32 + (lane >> 4) * 8;
    const f32x4* src = (const f32x4*)(w + (size_t)col * H_DIM + kb);
    f32x4 v0 = src[0], v1 = src[1];
    half8 h;
    #pragma unroll
    for (int j = 0; j < 4; ++j) { h[j] = (_Float16)v0[j]; h[4 + j] = (_Float16)v1[j]; }
    *(half8*)(wf + (size_t)gid * 8) = h;
}

// Fused: gi = x @ W^T (f16 MFMA, fp32 acc) -> GRU gates -> dot(lin_w) -> out
__global__ __launch_bounds__(256) void ping_main_kernel(
    const float* __restrict__ x, const _Float16* __restrict__ wf,
    const float* __restrict__ bias_ih, const float* __restrict__ bias_hh,
    const float* __restrict__ lin_w, const float* __restrict__ lin_b,
    float* __restrict__ out)
{
    __shared__ _Float16 shA[BM * LDA];
    __shared__ float sh_out[BM];

    const int t    = threadIdx.x;       // 0..255
    const int lane = t & 63;
    const int wv   = t >> 6;            // wave 0..3
    const int ln   = lane & 15;
    const int quad = lane >> 4;

    if (t < BM) sh_out[t] = 0.0f;

    const size_t row0 = (size_t)blockIdx.x * BM;

    f32x4 acc[6][4];
    #pragma unroll
    for (int i = 0; i < 6; ++i)
        #pragma unroll
        for (int rt = 0; rt < 4; ++rt)
            acc[i][rt] = (f32x4){0.f, 0.f, 0.f, 0.f};

    // staging mapping: thread -> (row, 16-float k-chunk)
    const int rs = t >> 2;              // 0..63
    const int kg = (t & 3) * 16;        // 0,16,32,48
    const float* xrow = x + (row0 + rs) * (size_t)H_DIM + kg;
    _Float16* sA = &shA[rs * LDA + kg];

    const half8* bbase = (const half8*)wf;

    for (int kb = 0; kb < H_DIM / 64; ++kb) {   // 16 iterations, BK=64
        __syncthreads();
        const f32x4* src = (const f32x4*)(xrow + kb * 64);
        f32x4 v0 = src[0], v1 = src[1], v2 = src[2], v3 = src[3];
        half8 h0, h1;
        #pragma unroll
        for (int j = 0; j < 4; ++j) {
            h0[j] = (_Float16)v0[j]; h0[4 + j] = (_Float16)v1[j];
            h1[j] = (_Float16)v2[j]; h1[4 + j] = (_Float16)v3[j];
        }
        *(half8*)sA       = h0;
        *(half8*)(sA + 8) = h1;
        __syncthreads();

        #pragma unroll
        for (int kt = 0; kt < 2; ++kt) {
            const int ktg = kb * 2 + kt;
            half8 a[4];
            #pragma unroll
            for (int rt = 0; rt < 4; ++rt)
                a[rt] = *(const half8*)&shA[(rt * 16 + ln) * LDA + kt * 32 + quad * 8];
            half8 b[6];
            #pragma unroll
            for (int i = 0; i < 6; ++i) {
                const int ct = ((i >> 1) * 8) + 2 * wv + (i & 1);
                b[i] = bbase[(size_t)(ct * 32 + ktg) * 64 + lane];
            }
            #pragma unroll
            for (int i = 0; i < 6; ++i)
                #pragma unroll
                for (int rt = 0; rt < 4; ++rt)
                    acc[i][rt] = __builtin_amdgcn_mfma_f32_16x16x32_f16(a[rt], b[i], acc[i][rt], 0, 0, 0);
        }
    }

    // Epilogue: per lane, columns g = 32*wv + 16*i + ln for i in {0,1};
    // acc[i] = r-part, acc[2+i] = z-part, acc[4+i] = n-part (same g, same lanes).
    float psum[4][4];
    #pragma unroll
    for (int rt = 0; rt < 4; ++rt)
        #pragma unroll
        for (int reg = 0; reg < 4; ++reg)
            psum[rt][reg] = 0.f;

    #pragma unroll
    for (int i = 0; i < 2; ++i) {
        const int g = 32 * wv + 16 * i + ln;
        const float b_ir = bias_ih[g];
        const float b_iz = bias_ih[G_DIM + g];
        const float b_in = bias_ih[2 * G_DIM + g];
        const float b_hr = bias_hh[g];
        const float b_hz = bias_hh[G_DIM + g];
        const float b_hn = bias_hh[2 * G_DIM + g];
        const float lw   = lin_w[g];
        #pragma unroll
        for (int rt = 0; rt < 4; ++rt) {
            #pragma unroll
            for (int reg = 0; reg < 4; ++reg) {
                const float r = sigmoidf_(acc[i][rt][reg] + b_ir + b_hr);
                const float z = sigmoidf_(acc[2 + i][rt][reg] + b_iz + b_hz);
                const float n = tanhf(acc[4 + i][rt][reg] + b_in + r * b_hn);
                psum[rt][reg] += lw * (1.0f - z) * n;
            }
        }
    }

    #pragma unroll
    for (int rt = 0; rt < 4; ++rt)
        #pragma unroll
        for (int reg = 0; reg < 4; ++reg) {
            const int row = rt * 16 + quad * 4 + reg;
            atomicAdd(&sh_out[row], psum[rt][reg]);
        }

    __syncthreads();
    if (t < BM) out[row0 + t] = sh_out[t] + lin_b[0];
}

extern "C" void kernel_launch(void* const* d_in, const int* in_sizes, int n_in,
                              void* d_out, int out_size, void* d_ws, size_t ws_size,
                              hipStream_t stream) {
    const float* x      = (const float*)d_in[0];
    const float* w_ih   = (const float*)d_in[1];
    // d_in[2] = weight_hh: unused (hidden state is always zero in the reference)
    const float* b_ih   = (const float*)d_in[3];
    const float* b_hh   = (const float*)d_in[4];
    const float* lin_w  = (const float*)d_in[5];
    const float* lin_b  = (const float*)d_in[6];
    float* out          = (float*)d_out;
    _Float16* wf        = (_Float16*)d_ws;   // 384*1024*2 = 768 KB scratch

    hipLaunchKernelGGL(prep_w_kernel, dim3((N_DIM / 16) * 32 * 64 / 256), dim3(256), 0, stream,
                       w_ih, wf);
    hipLaunchKernelGGL(ping_main_kernel, dim3(M_TOTAL / BM), dim3(256), 0, stream,
                       x, wf, b_ih, b_hh, lin_w, lin_b, out);
}